// Round 11
// baseline (162.743 us; speedup 1.0000x reference)
//
#include <hip/hip_runtime.h>

#define COLS  4096
#define C4    (COLS / 4)
#define TROWS 4096
#define PAIRS (TROWS - 1)   // 4095
#define PCH   32            // pairs per chunk (compile-time)
#define NCHK  128           // ceil(4095/32)

// ---------------------------------------------------------------------------
// Mergeable run record (verified absmax=0 rounds 3-10).
// Packed 16 B: x=hs y=ts z=ms w=bits[ hc:10 | tc:10 | mc:10 | ao:2 ]
// ---------------------------------------------------------------------------
struct Rec { float hs, hc, ts, tc, ms, mc, ao; };

__device__ inline Rec rec_merge(const Rec& L, const Rec& R) {
    Rec o;
    if (L.ao != 0.f && R.ao != 0.f) {
        o.hs = L.hs + R.hs; o.hc = L.hc + R.hc;
        o.ts = o.hs;        o.tc = o.hc;
        o.ms = 0.f; o.mc = 0.f; o.ao = 1.f;
    } else if (L.ao != 0.f) {
        o.hs = L.hs + R.hs; o.hc = L.hc + R.hc;
        o.ts = R.ts; o.tc = R.tc;
        o.ms = R.ms; o.mc = R.mc; o.ao = 0.f;
    } else if (R.ao != 0.f) {
        o.hs = L.hs; o.hc = L.hc;
        o.ts = L.ts + R.hs; o.tc = L.tc + R.hc;
        o.ms = L.ms; o.mc = L.mc; o.ao = 0.f;
    } else {
        o.hs = L.hs; o.hc = L.hc;
        o.ts = R.ts; o.tc = R.tc;
        float js = L.ts + R.hs, jc = L.tc + R.hc;
        bool v = jc > 0.f;
        o.ms = L.ms + R.ms + (v ? js / jc : 0.f);
        o.mc = L.mc + R.mc + (v ? 1.f : 0.f);
        o.ao = 0.f;
    }
    return o;
}

__device__ inline Rec rec16_load(const float4* base, size_t idx) {
    float4 a = base[idx];
    unsigned u = __float_as_uint(a.w);
    Rec r;
    r.hs = a.x; r.ts = a.y; r.ms = a.z;
    r.hc = (float)(u & 1023u);
    r.tc = (float)((u >> 10) & 1023u);
    r.mc = (float)((u >> 20) & 1023u);
    r.ao = (float)(u >> 30);
    return r;
}
__device__ inline Rec rec32_load(const float4* base, size_t idx) {
    float4 a = base[idx * 2], b = base[idx * 2 + 1];
    Rec r; r.hs = a.x; r.hc = a.y; r.ts = a.z; r.tc = a.w;
    r.ms = b.x; r.mc = b.y; r.ao = b.z; return r;
}
__device__ inline void rec32_store(float4* base, size_t idx, const Rec& r) {
    base[idx * 2]     = make_float4(r.hs, r.hc, r.ts, r.tc);
    base[idx * 2 + 1] = make_float4(r.ms, r.mc, r.ao, 0.f);
}

// ---------------------------------------------------------------------------
// Phase 1: deep-ILP register scan. Each thread owns 4 cols x 32 pairs,
// processed as 4 straight-line "eighths": 16 loads (8 rows x P,S) with ALL
// destinations live until consumption -> the allocator must issue the whole
// batch before the first waitcnt (cannot serialize). amdgpu_waves_per_eu(4,4)
// pins the budget at 128 VGPR so the compiler keeps the batch in registers.
// Scan state carries across eighths (one record per thread at the end).
// ---------------------------------------------------------------------------
__global__ __launch_bounds__(256)
__attribute__((amdgpu_waves_per_eu(4, 4)))
void msi_phase1(const float4* __restrict__ p4, const float4* __restrict__ s4,
                float4* __restrict__ recs) {
    int g = blockIdx.x * blockDim.x + threadIdx.x;   // column group (4 cols)
    int c = blockIdx.y;
    const int t0 = c * PCH;
    int t1 = t0 + PCH; if (t1 > PAIRS) t1 = PAIRS;
    const int nr = t1 - t0;                          // 32 (31 for last chunk)

    const float4* Pp = p4 + (size_t)t0 * C4 + g;
    const float4* Sp = s4 + (size_t)t0 * C4 + g;

    float cs[4] = {0.f, 0.f, 0.f, 0.f};
    int   cc[4] = {0, 0, 0, 0};
    float hs[4] = {0.f, 0.f, 0.f, 0.f};
    int   hc[4] = {0, 0, 0, 0};
    int   hd[4] = {0, 0, 0, 0};
    float ms[4] = {0.f, 0.f, 0.f, 0.f};
    int   mc[4] = {0, 0, 0, 0};

    float4 pv = Pp[0];
    float4 sv = Sp[0];
    float    pprev[4] = {pv.x, pv.y, pv.z, pv.w};
    unsigned sprev[4] = {__float_as_uint(sv.x), __float_as_uint(sv.y),
                         __float_as_uint(sv.z), __float_as_uint(sv.w)};

    #pragma unroll
    for (int e = 0; e < 4; ++e) {
        // ---- batch-load 8 rows of P and S (16 loads, all dests live) ----
        float4 lp_[8], ls_[8];
        #pragma unroll
        for (int j = 0; j < 8; ++j) {
            int rr = 8 * e + 1 + j;                  // row offset 1..32
            int cl = (rr <= nr) ? rr : nr;           // clamp (phantom row)
            lp_[j] = Pp[(size_t)cl * C4];
            ls_[j] = Sp[(size_t)cl * C4];
        }
        // ---- consume 8 pairs ----
        #pragma unroll
        for (int j = 0; j < 8; ++j) {
            int pi = 8 * e + j;                      // pair index in chunk
            bool act = pi < nr;
            float    pcur[4] = {lp_[j].x, lp_[j].y, lp_[j].z, lp_[j].w};
            unsigned scur[4] = {__float_as_uint(ls_[j].x), __float_as_uint(ls_[j].y),
                                __float_as_uint(ls_[j].z), __float_as_uint(ls_[j].w)};
            #pragma unroll
            for (int k = 0; k < 4; ++k) {
                float d = pcur[k] - pprev[k];
                bool same = (scur[k] == sprev[k]);
                bool firstk = act && !same && !hd[k];
                bool interior = act && !same && hd[k] && (cc[k] > 0);
                hs[k] = firstk ? cs[k] : hs[k];
                hc[k] = firstk ? cc[k] : hc[k];
                float mean = cs[k] * __builtin_amdgcn_rcpf((float)cc[k]);
                ms[k] += interior ? mean : 0.f;
                mc[k] += interior ? 1 : 0;
                hd[k] = hd[k] | ((act && !same) ? 1 : 0);
                cs[k] = act ? (same ? cs[k] + d * d : 0.f) : cs[k];
                cc[k] = act ? (same ? cc[k] + 1 : 0) : cc[k];
                pprev[k] = pcur[k];
                sprev[k] = scur[k];
            }
        }
    }

    // Emit 4 packed 16 B records (64 B contiguous per thread).
    #pragma unroll
    for (int k = 0; k < 4; ++k) {
        int r = 4 * g + k;
        float4 a;
        if (!hd[k]) {
            unsigned u = (unsigned)cc[k] | ((unsigned)cc[k] << 10) | (3u << 30);
            a = make_float4(cs[k], cs[k], 0.f, __uint_as_float(u));
        } else {
            unsigned u = (unsigned)hc[k] | ((unsigned)cc[k] << 10) |
                         ((unsigned)mc[k] << 20);
            a = make_float4(hs[k], cs[k], ms[k], __uint_as_float(u));
        }
        recs[(size_t)c * COLS + r] = a;
    }
}

// ---------------------------------------------------------------------------
// Phase 2a: merge G consecutive chunk-records per column into a 32 B super.
// ---------------------------------------------------------------------------
__global__ void msi_phase2a(const float4* __restrict__ recs, float4* __restrict__ supers,
                            int G) {
    int r = blockIdx.x * blockDim.x + threadIdx.x;
    int sup = blockIdx.y;
    size_t base = (size_t)sup * G * COLS + r;
    Rec acc = rec16_load(recs, base);
    #pragma unroll 4
    for (int j = 1; j < G; ++j) {
        Rec nxt = rec16_load(recs, base + (size_t)j * COLS);
        acc = rec_merge(acc, nxt);
    }
    rec32_store(supers, (size_t)sup * COLS + r, acc);
}

// ---------------------------------------------------------------------------
// Phase 2b: merge NSUP supers per column, finalize, block-reduce in double.
// ---------------------------------------------------------------------------
__global__ void msi_phase2b(const float4* __restrict__ supers, double* __restrict__ partials,
                            int NSUP) {
    int r = blockIdx.x * blockDim.x + threadIdx.x;
    Rec acc = rec32_load(supers, r);
    for (int j = 1; j < NSUP; ++j)
        acc = rec_merge(acc, rec32_load(supers, (size_t)j * COLS + r));

    double msum, mcnt;
    if (acc.ao != 0.f) {
        bool v = acc.hc > 0.f;
        msum = v ? (double)(acc.hs / acc.hc) : 0.0;
        mcnt = v ? 1.0 : 0.0;
    } else {
        msum = (double)acc.ms; mcnt = (double)acc.mc;
        if (acc.hc > 0.f) { msum += (double)(acc.hs / acc.hc); mcnt += 1.0; }
        if (acc.tc > 0.f) { msum += (double)(acc.ts / acc.tc); mcnt += 1.0; }
    }

    __shared__ double ls[256];
    __shared__ double lc[256];
    int tid = threadIdx.x;
    ls[tid] = msum; lc[tid] = mcnt;
    __syncthreads();
    for (int off = 128; off > 0; off >>= 1) {
        if (tid < off) { ls[tid] += ls[tid + off]; lc[tid] += lc[tid + off]; }
        __syncthreads();
    }
    if (tid == 0) {
        partials[blockIdx.x * 2 + 0] = ls[0];
        partials[blockIdx.x * 2 + 1] = lc[0];
    }
}

__global__ void msi_phase3(const double* __restrict__ partials, int nparts,
                           float* __restrict__ out) {
    int tid = threadIdx.x;
    double msum = 0.0, mcnt = 0.0;
    if (tid < nparts) {
        msum = partials[tid * 2 + 0];
        mcnt = partials[tid * 2 + 1];
    }
    for (int off = 32; off > 0; off >>= 1) {
        msum += __shfl_down(msum, off);
        mcnt += __shfl_down(mcnt, off);
    }
    if (tid == 0) out[0] = (mcnt > 0.0) ? (float)(msum / mcnt) : 0.f;
}

extern "C" void kernel_launch(void* const* d_in, const int* in_sizes, int n_in,
                              void* d_out, int out_size, void* d_ws, size_t ws_size,
                              hipStream_t stream) {
    const float4* p = (const float4*)d_in[0];
    const float4* s = (const float4*)d_in[1];   // int bits compared as uint
    float* out = (float*)d_out;

    const int nblocks2 = COLS / 256;  // 16
    const int NC = NCHK;              // 128 chunks of 32 pairs
    const int G = 16;
    const int NSUP = NC / G;          // 8

    float4* recs     = (float4*)d_ws;                 // NC*COLS packed 16B recs (8 MB)
    float4* supers   = recs + (size_t)NC * COLS;      // NSUP*COLS 32B recs (1 MB)
    double* partials = (double*)(supers + (size_t)NSUP * COLS * 2);

    dim3 g1(C4 / 256, NC);         // (4, 128) blocks of 256
    msi_phase1<<<g1, 256, 0, stream>>>(p, s, recs);
    dim3 g2a(COLS / 256, NSUP);
    msi_phase2a<<<g2a, 256, 0, stream>>>(recs, supers, G);
    msi_phase2b<<<nblocks2, 256, 0, stream>>>(supers, partials, NSUP);
    msi_phase3<<<1, 64, 0, stream>>>(partials, nblocks2, out);
}

// Round 12
// 47.431 us; speedup vs baseline: 3.4311x; 3.4311x over previous
//
#include <hip/hip_runtime.h>

#define COLS  4096
#define C4    (COLS / 4)
#define TROWS 4096
#define PAIRS (TROWS - 1)   // 4095
#define WCOLS 1024          // cols per block
#define SR    4             // pair-rows per stage
#define NBUF  4             // ring depth
#define PCH   64            // pairs per chunk
#define NC    64            // chunks -> 4 x 64 = 256 blocks = 1/CU

// ---------------------------------------------------------------------------
// Mergeable run record (verified absmax=0 rounds 3-11).
// Packed 16 B: x=hs y=ts z=ms w=bits[ hc:10 | tc:10 | mc:10 | ao:2 ]
// ---------------------------------------------------------------------------
struct Rec { float hs, hc, ts, tc, ms, mc, ao; };

__device__ inline Rec rec_merge(const Rec& L, const Rec& R) {
    Rec o;
    if (L.ao != 0.f && R.ao != 0.f) {
        o.hs = L.hs + R.hs; o.hc = L.hc + R.hc;
        o.ts = o.hs;        o.tc = o.hc;
        o.ms = 0.f; o.mc = 0.f; o.ao = 1.f;
    } else if (L.ao != 0.f) {
        o.hs = L.hs + R.hs; o.hc = L.hc + R.hc;
        o.ts = R.ts; o.tc = R.tc;
        o.ms = R.ms; o.mc = R.mc; o.ao = 0.f;
    } else if (R.ao != 0.f) {
        o.hs = L.hs; o.hc = L.hc;
        o.ts = L.ts + R.hs; o.tc = L.tc + R.hc;
        o.ms = L.ms; o.mc = L.mc; o.ao = 0.f;
    } else {
        o.hs = L.hs; o.hc = L.hc;
        o.ts = R.ts; o.tc = R.tc;
        float js = L.ts + R.hs, jc = L.tc + R.hc;
        bool v = jc > 0.f;
        o.ms = L.ms + R.ms + (v ? js / jc : 0.f);
        o.mc = L.mc + R.mc + (v ? 1.f : 0.f);
        o.ao = 0.f;
    }
    return o;
}

__device__ inline Rec rec16_load(const float4* base, size_t idx) {
    float4 a = base[idx];
    unsigned u = __float_as_uint(a.w);
    Rec r;
    r.hs = a.x; r.ts = a.y; r.ms = a.z;
    r.hc = (float)(u & 1023u);
    r.tc = (float)((u >> 10) & 1023u);
    r.mc = (float)((u >> 20) & 1023u);
    r.ao = (float)(u >> 30);
    return r;
}
__device__ inline Rec rec32_load(const float4* base, size_t idx) {
    float4 a = base[idx * 2], b = base[idx * 2 + 1];
    Rec r; r.hs = a.x; r.hc = a.y; r.ts = a.z; r.tc = a.w;
    r.ms = b.x; r.mc = b.y; r.ao = b.z; return r;
}
__device__ inline void rec32_store(float4* base, size_t idx, const Rec& r) {
    base[idx * 2]     = make_float4(r.hs, r.hc, r.ts, r.tc);
    base[idx * 2 + 1] = make_float4(r.ms, r.mc, r.ao, 0.f);
}

// async 16B/lane global -> LDS
__device__ __forceinline__ void async16(const void* g, void* l) {
    __builtin_amdgcn_global_load_lds(
        (const __attribute__((address_space(1))) void*)g,
        (__attribute__((address_space(3))) void*)l, 16, 0, 0);
}

// ---------------------------------------------------------------------------
// Phase 1: 4-deep wave-private gload_lds ring. 256-thread block owns 1024
// cols; stage = 4 rows (32 KB/block); ring of 4 stages (128 KB) + boundary
// (8 KB) = 136 KB LDS -> 1 block/CU. Each wave stages/consumes ONLY its own
// 256-col slice -> zero barriers. Issue runs 3 stages ahead of consume with
// counted vmcnt -> ~96 KB/CU in flight continuously.
// ---------------------------------------------------------------------------
__global__ __launch_bounds__(256)
void msi_phase1(const float4* __restrict__ p4, const int4* __restrict__ s4,
                float4* __restrict__ recs) {
    __shared__ __align__(16) float lp[NBUF][SR][WCOLS];   // 64 KB
    __shared__ __align__(16) int   lsd[NBUF][SR][WCOLS];  // 64 KB
    __shared__ __align__(16) float lpB[WCOLS];            // 4 KB
    __shared__ __align__(16) int   lsB[WCOLS];            // 4 KB

    const int tid  = threadIdx.x;                 // owns cols 4*tid..4*tid+3 (block-local)
    const int wave = tid >> 6, lane = tid & 63;
    const int colq = blockIdx.x;                  // column quarter 0..3
    const int c    = blockIdx.y;                  // chunk 0..NC-1
    const int t0 = c * PCH;
    int t1 = t0 + PCH; if (t1 > PAIRS) t1 = PAIRS;
    const int nr  = t1 - t0;                      // 64 (63 last)
    const int nst = (nr + SR - 1) / SR;           // 16

    const float4* gp = p4 + colq * (WCOLS / 4) + (wave << 6) + lane;
    const int4*   gs = s4 + colq * (WCOLS / 4) + (wave << 6) + lane;
    const int woff = wave << 8;                   // wave slice: 256 floats = 1 KB

    auto issue = [&](int st) {                    // stage st: rows t0+st*SR+1 .. +SR
        int b = st & (NBUF - 1);
        #pragma unroll
        for (int j = 0; j < SR; ++j) {
            int r = t0 + st * SR + 1 + j; if (r > t1) r = t1;   // phantom, never read
            async16(gp + (size_t)r * C4, &lp[b][j][0] + woff);
            async16(gs + (size_t)r * C4, &lsd[b][j][0] + woff);
        }
    };

    float cs[4] = {0.f, 0.f, 0.f, 0.f};
    int   cc[4] = {0, 0, 0, 0};
    float hs[4] = {0.f, 0.f, 0.f, 0.f};
    int   hc[4] = {0, 0, 0, 0};
    int   hd[4] = {0, 0, 0, 0};
    float ms[4] = {0.f, 0.f, 0.f, 0.f};
    int   mc[4] = {0, 0, 0, 0};
    float pprev[4]; int sprev[4];

    // prologue: boundary row + 3 stages (26 loads outstanding max)
    async16(gp + (size_t)t0 * C4, &lpB[0] + woff);
    async16(gs + (size_t)t0 * C4, &lsB[0] + woff);
    issue(0); issue(1); issue(2);                 // nst >= 16 always

    for (int s = 0; s < nst; ++s) {
        // free buffer = (s-1)&3 == (s+3)&3; its ds_reads retired last iter.
        asm volatile("s_waitcnt lgkmcnt(0)" ::: "memory");
        if (s + 3 < nst) issue(s + 3);

        int ahead = nst - 1 - s; if (ahead > 3) ahead = 3;
        // stage s complete when outstanding <= ahead*8 (in-order vmcnt)
        if (ahead == 3)      { asm volatile("s_waitcnt vmcnt(24)" ::: "memory"); }
        else if (ahead == 2) { asm volatile("s_waitcnt vmcnt(16)" ::: "memory"); }
        else if (ahead == 1) { asm volatile("s_waitcnt vmcnt(8)"  ::: "memory"); }
        else                 { asm volatile("s_waitcnt vmcnt(0)"  ::: "memory"); }
        __builtin_amdgcn_sched_barrier(0);

        if (s == 0) {                             // boundary row (covered by wait)
            float4 P = *(const float4*)&lpB[tid << 2];
            int4   S = *(const int4*)&lsB[tid << 2];
            pprev[0] = P.x; pprev[1] = P.y; pprev[2] = P.z; pprev[3] = P.w;
            sprev[0] = S.x; sprev[1] = S.y; sprev[2] = S.z; sprev[3] = S.w;
        }

        const int b = s & (NBUF - 1);
        int jmax = nr - s * SR; if (jmax > SR) jmax = SR;
        #pragma unroll
        for (int j = 0; j < SR; ++j) {
            if (j >= jmax) break;
            float4 PV = *(const float4*)&lp[b][j][tid << 2];
            int4   SV = *(const int4*)&lsd[b][j][tid << 2];
            float pcur[4] = {PV.x, PV.y, PV.z, PV.w};
            int   scur[4] = {SV.x, SV.y, SV.z, SV.w};
            #pragma unroll
            for (int k = 0; k < 4; ++k) {
                float d = pcur[k] - pprev[k];
                bool same = (scur[k] == sprev[k]);
                bool firstk = !same && !hd[k];
                bool interior = !same && hd[k] && (cc[k] > 0);
                hs[k] = firstk ? cs[k] : hs[k];
                hc[k] = firstk ? cc[k] : hc[k];
                float mean = cs[k] * __builtin_amdgcn_rcpf((float)cc[k]);
                ms[k] += interior ? mean : 0.f;
                mc[k] += interior ? 1 : 0;
                hd[k] = hd[k] | (same ? 0 : 1);
                cs[k] = same ? cs[k] + d * d : 0.f;
                cc[k] = same ? cc[k] + 1 : 0;
                pprev[k] = pcur[k];
                sprev[k] = scur[k];
            }
        }
    }

    // Emit 4 packed 16 B records (64 B contiguous per thread).
    #pragma unroll
    for (int k = 0; k < 4; ++k) {
        int r = colq * WCOLS + 4 * tid + k;
        float4 a;
        if (!hd[k]) {
            unsigned u = (unsigned)cc[k] | ((unsigned)cc[k] << 10) | (3u << 30);
            a = make_float4(cs[k], cs[k], 0.f, __uint_as_float(u));
        } else {
            unsigned u = (unsigned)hc[k] | ((unsigned)cc[k] << 10) |
                         ((unsigned)mc[k] << 20);
            a = make_float4(hs[k], cs[k], ms[k], __uint_as_float(u));
        }
        recs[(size_t)c * COLS + r] = a;
    }
}

// ---------------------------------------------------------------------------
// Phase 2a: merge G consecutive chunk-records per column into a 32 B super.
// ---------------------------------------------------------------------------
__global__ void msi_phase2a(const float4* __restrict__ recs, float4* __restrict__ supers,
                            int G) {
    int r = blockIdx.x * blockDim.x + threadIdx.x;
    int sup = blockIdx.y;
    size_t base = (size_t)sup * G * COLS + r;
    Rec acc = rec16_load(recs, base);
    #pragma unroll 4
    for (int j = 1; j < G; ++j) {
        Rec nxt = rec16_load(recs, base + (size_t)j * COLS);
        acc = rec_merge(acc, nxt);
    }
    rec32_store(supers, (size_t)sup * COLS + r, acc);
}

// ---------------------------------------------------------------------------
// Phase 2b: merge NSUP supers per column, finalize, block-reduce in double.
// ---------------------------------------------------------------------------
__global__ void msi_phase2b(const float4* __restrict__ supers, double* __restrict__ partials,
                            int NSUP) {
    int r = blockIdx.x * blockDim.x + threadIdx.x;
    Rec acc = rec32_load(supers, r);
    for (int j = 1; j < NSUP; ++j)
        acc = rec_merge(acc, rec32_load(supers, (size_t)j * COLS + r));

    double msum, mcnt;
    if (acc.ao != 0.f) {
        bool v = acc.hc > 0.f;
        msum = v ? (double)(acc.hs / acc.hc) : 0.0;
        mcnt = v ? 1.0 : 0.0;
    } else {
        msum = (double)acc.ms; mcnt = (double)acc.mc;
        if (acc.hc > 0.f) { msum += (double)(acc.hs / acc.hc); mcnt += 1.0; }
        if (acc.tc > 0.f) { msum += (double)(acc.ts / acc.tc); mcnt += 1.0; }
    }

    __shared__ double ls[256];
    __shared__ double lc[256];
    int tid = threadIdx.x;
    ls[tid] = msum; lc[tid] = mcnt;
    __syncthreads();
    for (int off = 128; off > 0; off >>= 1) {
        if (tid < off) { ls[tid] += ls[tid + off]; lc[tid] += lc[tid + off]; }
        __syncthreads();
    }
    if (tid == 0) {
        partials[blockIdx.x * 2 + 0] = ls[0];
        partials[blockIdx.x * 2 + 1] = lc[0];
    }
}

__global__ void msi_phase3(const double* __restrict__ partials, int nparts,
                           float* __restrict__ out) {
    int tid = threadIdx.x;
    double msum = 0.0, mcnt = 0.0;
    if (tid < nparts) {
        msum = partials[tid * 2 + 0];
        mcnt = partials[tid * 2 + 1];
    }
    for (int off = 32; off > 0; off >>= 1) {
        msum += __shfl_down(msum, off);
        mcnt += __shfl_down(mcnt, off);
    }
    if (tid == 0) out[0] = (mcnt > 0.0) ? (float)(msum / mcnt) : 0.f;
}

extern "C" void kernel_launch(void* const* d_in, const int* in_sizes, int n_in,
                              void* d_out, int out_size, void* d_ws, size_t ws_size,
                              hipStream_t stream) {
    const float4* p = (const float4*)d_in[0];
    const int4*   s = (const int4*)d_in[1];
    float* out = (float*)d_out;

    const int nblocks2 = COLS / 256;  // 16
    const int G = 16;
    const int NSUP = NC / G;          // 4

    float4* recs     = (float4*)d_ws;                 // NC*COLS packed 16B (4 MB)
    float4* supers   = recs + (size_t)NC * COLS;      // NSUP*COLS 32B (0.5 MB)
    double* partials = (double*)(supers + (size_t)NSUP * COLS * 2);

    dim3 g1(4, NC);                // 256 blocks of 256 = 1 block/CU
    msi_phase1<<<g1, 256, 0, stream>>>(p, s, recs);
    dim3 g2a(COLS / 256, NSUP);
    msi_phase2a<<<g2a, 256, 0, stream>>>(recs, supers, G);
    msi_phase2b<<<nblocks2, 256, 0, stream>>>(supers, partials, NSUP);
    msi_phase3<<<1, 64, 0, stream>>>(partials, nblocks2, out);
}

// Round 13
// 47.007 us; speedup vs baseline: 3.4621x; 1.0090x over previous
//
#include <hip/hip_runtime.h>

#define COLS  4096
#define C4    (COLS / 4)
#define TROWS 4096
#define PAIRS (TROWS - 1)   // 4095
#define BCOLS 1024          // cols per block
#define SR    2             // pair-rows per stage
#define NBUF  4             // ring depth
#define PCH   32            // pairs per chunk
#define NC    128           // chunks -> (4,128) = 512 blocks = 2/CU

// ---------------------------------------------------------------------------
// Mergeable run record (verified absmax=0 rounds 3-12).
// Packed 16 B: x=hs y=ts z=ms w=bits[ hc:10 | tc:10 | mc:10 | ao:2 ]
// ---------------------------------------------------------------------------
struct Rec { float hs, hc, ts, tc, ms, mc, ao; };

__device__ inline Rec rec_merge(const Rec& L, const Rec& R) {
    Rec o;
    if (L.ao != 0.f && R.ao != 0.f) {
        o.hs = L.hs + R.hs; o.hc = L.hc + R.hc;
        o.ts = o.hs;        o.tc = o.hc;
        o.ms = 0.f; o.mc = 0.f; o.ao = 1.f;
    } else if (L.ao != 0.f) {
        o.hs = L.hs + R.hs; o.hc = L.hc + R.hc;
        o.ts = R.ts; o.tc = R.tc;
        o.ms = R.ms; o.mc = R.mc; o.ao = 0.f;
    } else if (R.ao != 0.f) {
        o.hs = L.hs; o.hc = L.hc;
        o.ts = L.ts + R.hs; o.tc = L.tc + R.hc;
        o.ms = L.ms; o.mc = L.mc; o.ao = 0.f;
    } else {
        o.hs = L.hs; o.hc = L.hc;
        o.ts = R.ts; o.tc = R.tc;
        float js = L.ts + R.hs, jc = L.tc + R.hc;
        bool v = jc > 0.f;
        o.ms = L.ms + R.ms + (v ? js / jc : 0.f);
        o.mc = L.mc + R.mc + (v ? 1.f : 0.f);
        o.ao = 0.f;
    }
    return o;
}

__device__ inline Rec rec16_load(const float4* base, size_t idx) {
    float4 a = base[idx];
    unsigned u = __float_as_uint(a.w);
    Rec r;
    r.hs = a.x; r.ts = a.y; r.ms = a.z;
    r.hc = (float)(u & 1023u);
    r.tc = (float)((u >> 10) & 1023u);
    r.mc = (float)((u >> 20) & 1023u);
    r.ao = (float)(u >> 30);
    return r;
}
__device__ inline Rec rec32_load(const float4* base, size_t idx) {
    float4 a = base[idx * 2], b = base[idx * 2 + 1];
    Rec r; r.hs = a.x; r.hc = a.y; r.ts = a.z; r.tc = a.w;
    r.ms = b.x; r.mc = b.y; r.ao = b.z; return r;
}
__device__ inline void rec32_store(float4* base, size_t idx, const Rec& r) {
    base[idx * 2]     = make_float4(r.hs, r.hc, r.ts, r.tc);
    base[idx * 2 + 1] = make_float4(r.ms, r.mc, r.ao, 0.f);
}

// async 16B/lane global -> LDS with NT cache policy (aux=2: non-temporal hint;
// cache-policy bits are semantics-neutral). Tests whether L2/L3 insertion is
// the rate limiter.
__device__ __forceinline__ void async16nt(const void* g, void* l) {
    __builtin_amdgcn_global_load_lds(
        (const __attribute__((address_space(1))) void*)g,
        (__attribute__((address_space(3))) void*)l, 16, 0, 2);
}

// ---------------------------------------------------------------------------
// Phase 1: wave-private 4-deep ring (NBUF=4, SR=2) at 2 blocks/CU.
// 8 waves/CU x 12 KB/wave in flight = 96 KB/CU, zero barriers, counted vmcnt
// never drains mid-loop. Combines r6's wave count with r12's pipeline depth.
// ---------------------------------------------------------------------------
__global__ __launch_bounds__(256)
void msi_phase1(const float4* __restrict__ p4, const int4* __restrict__ s4,
                float4* __restrict__ recs) {
    __shared__ __align__(16) float lp[NBUF][SR][BCOLS];   // 32 KB
    __shared__ __align__(16) int   lsd[NBUF][SR][BCOLS];  // 32 KB
    __shared__ __align__(16) float lpB[BCOLS];            // 4 KB
    __shared__ __align__(16) int   lsB[BCOLS];            // 4 KB

    const int tid  = threadIdx.x;
    const int wave = tid >> 6, lane = tid & 63;
    const int colq = blockIdx.x;                  // column quarter 0..3
    const int c    = blockIdx.y;                  // chunk 0..NC-1
    const int t0 = c * PCH;
    int t1 = t0 + PCH; if (t1 > PAIRS) t1 = PAIRS;
    const int nr  = t1 - t0;                      // 32 (31 last)
    const int nst = (nr + SR - 1) / SR;           // 16

    const float4* gp = p4 + colq * (BCOLS / 4) + (wave << 6) + lane;
    const int4*   gs = s4 + colq * (BCOLS / 4) + (wave << 6) + lane;
    const int woff = wave << 8;                   // wave slice: 256 floats = 1 KB

    auto issue = [&](int st) {                    // stage st: rows t0+st*SR+1 .. +SR
        int b = st & (NBUF - 1);
        #pragma unroll
        for (int j = 0; j < SR; ++j) {
            int r = t0 + st * SR + 1 + j; if (r > t1) r = t1;   // phantom, never read
            async16nt(gp + (size_t)r * C4, &lp[b][j][0] + woff);
            async16nt(gs + (size_t)r * C4, &lsd[b][j][0] + woff);
        }
    };

    float cs[4] = {0.f, 0.f, 0.f, 0.f};
    int   cc[4] = {0, 0, 0, 0};
    float hs[4] = {0.f, 0.f, 0.f, 0.f};
    int   hc[4] = {0, 0, 0, 0};
    int   hd[4] = {0, 0, 0, 0};
    float ms[4] = {0.f, 0.f, 0.f, 0.f};
    int   mc[4] = {0, 0, 0, 0};
    float pprev[4]; int sprev[4];

    // prologue: boundary row + 3 stages (14 loads outstanding)
    async16nt(gp + (size_t)t0 * C4, &lpB[0] + woff);
    async16nt(gs + (size_t)t0 * C4, &lsB[0] + woff);
    issue(0); issue(1); issue(2);                 // nst = 16 always >= 4

    for (int s = 0; s < nst; ++s) {
        // buffer being refilled = (s+3)&3; its ds_reads retired 4 iters ago.
        asm volatile("s_waitcnt lgkmcnt(0)" ::: "memory");
        if (s + 3 < nst) issue(s + 3);

        int ahead = nst - 1 - s; if (ahead > 3) ahead = 3;
        // stage s complete when outstanding <= ahead*4 (in-order vmcnt)
        if (ahead == 3)      { asm volatile("s_waitcnt vmcnt(12)" ::: "memory"); }
        else if (ahead == 2) { asm volatile("s_waitcnt vmcnt(8)"  ::: "memory"); }
        else if (ahead == 1) { asm volatile("s_waitcnt vmcnt(4)"  ::: "memory"); }
        else                 { asm volatile("s_waitcnt vmcnt(0)"  ::: "memory"); }
        __builtin_amdgcn_sched_barrier(0);

        if (s == 0) {                             // boundary row (covered by wait)
            float4 P = *(const float4*)&lpB[tid << 2];
            int4   S = *(const int4*)&lsB[tid << 2];
            pprev[0] = P.x; pprev[1] = P.y; pprev[2] = P.z; pprev[3] = P.w;
            sprev[0] = S.x; sprev[1] = S.y; sprev[2] = S.z; sprev[3] = S.w;
        }

        const int b = s & (NBUF - 1);
        int jmax = nr - s * SR; if (jmax > SR) jmax = SR;
        #pragma unroll
        for (int j = 0; j < SR; ++j) {
            if (j >= jmax) break;
            float4 PV = *(const float4*)&lp[b][j][tid << 2];
            int4   SV = *(const int4*)&lsd[b][j][tid << 2];
            float pcur[4] = {PV.x, PV.y, PV.z, PV.w};
            int   scur[4] = {SV.x, SV.y, SV.z, SV.w};
            #pragma unroll
            for (int k = 0; k < 4; ++k) {
                float d = pcur[k] - pprev[k];
                bool same = (scur[k] == sprev[k]);
                bool firstk = !same && !hd[k];
                bool interior = !same && hd[k] && (cc[k] > 0);
                hs[k] = firstk ? cs[k] : hs[k];
                hc[k] = firstk ? cc[k] : hc[k];
                float mean = cs[k] * __builtin_amdgcn_rcpf((float)cc[k]);
                ms[k] += interior ? mean : 0.f;
                mc[k] += interior ? 1 : 0;
                hd[k] = hd[k] | (same ? 0 : 1);
                cs[k] = same ? cs[k] + d * d : 0.f;
                cc[k] = same ? cc[k] + 1 : 0;
                pprev[k] = pcur[k];
                sprev[k] = scur[k];
            }
        }
    }

    // Emit 4 packed 16 B records (64 B contiguous per thread).
    #pragma unroll
    for (int k = 0; k < 4; ++k) {
        int r = colq * BCOLS + 4 * tid + k;
        float4 a;
        if (!hd[k]) {
            unsigned u = (unsigned)cc[k] | ((unsigned)cc[k] << 10) | (3u << 30);
            a = make_float4(cs[k], cs[k], 0.f, __uint_as_float(u));
        } else {
            unsigned u = (unsigned)hc[k] | ((unsigned)cc[k] << 10) |
                         ((unsigned)mc[k] << 20);
            a = make_float4(hs[k], cs[k], ms[k], __uint_as_float(u));
        }
        recs[(size_t)c * COLS + r] = a;
    }
}

// ---------------------------------------------------------------------------
// Phase 2a: merge G consecutive chunk-records per column into a 32 B super.
// ---------------------------------------------------------------------------
__global__ void msi_phase2a(const float4* __restrict__ recs, float4* __restrict__ supers,
                            int G) {
    int r = blockIdx.x * blockDim.x + threadIdx.x;
    int sup = blockIdx.y;
    size_t base = (size_t)sup * G * COLS + r;
    Rec acc = rec16_load(recs, base);
    #pragma unroll 4
    for (int j = 1; j < G; ++j) {
        Rec nxt = rec16_load(recs, base + (size_t)j * COLS);
        acc = rec_merge(acc, nxt);
    }
    rec32_store(supers, (size_t)sup * COLS + r, acc);
}

// ---------------------------------------------------------------------------
// Phase 2b: merge NSUP supers per column, finalize, block-reduce in double.
// ---------------------------------------------------------------------------
__global__ void msi_phase2b(const float4* __restrict__ supers, double* __restrict__ partials,
                            int NSUP) {
    int r = blockIdx.x * blockDim.x + threadIdx.x;
    Rec acc = rec32_load(supers, r);
    for (int j = 1; j < NSUP; ++j)
        acc = rec_merge(acc, rec32_load(supers, (size_t)j * COLS + r));

    double msum, mcnt;
    if (acc.ao != 0.f) {
        bool v = acc.hc > 0.f;
        msum = v ? (double)(acc.hs / acc.hc) : 0.0;
        mcnt = v ? 1.0 : 0.0;
    } else {
        msum = (double)acc.ms; mcnt = (double)acc.mc;
        if (acc.hc > 0.f) { msum += (double)(acc.hs / acc.hc); mcnt += 1.0; }
        if (acc.tc > 0.f) { msum += (double)(acc.ts / acc.tc); mcnt += 1.0; }
    }

    __shared__ double ls[256];
    __shared__ double lc[256];
    int tid = threadIdx.x;
    ls[tid] = msum; lc[tid] = mcnt;
    __syncthreads();
    for (int off = 128; off > 0; off >>= 1) {
        if (tid < off) { ls[tid] += ls[tid + off]; lc[tid] += lc[tid + off]; }
        __syncthreads();
    }
    if (tid == 0) {
        partials[blockIdx.x * 2 + 0] = ls[0];
        partials[blockIdx.x * 2 + 1] = lc[0];
    }
}

__global__ void msi_phase3(const double* __restrict__ partials, int nparts,
                           float* __restrict__ out) {
    int tid = threadIdx.x;
    double msum = 0.0, mcnt = 0.0;
    if (tid < nparts) {
        msum = partials[tid * 2 + 0];
        mcnt = partials[tid * 2 + 1];
    }
    for (int off = 32; off > 0; off >>= 1) {
        msum += __shfl_down(msum, off);
        mcnt += __shfl_down(mcnt, off);
    }
    if (tid == 0) out[0] = (mcnt > 0.0) ? (float)(msum / mcnt) : 0.f;
}

extern "C" void kernel_launch(void* const* d_in, const int* in_sizes, int n_in,
                              void* d_out, int out_size, void* d_ws, size_t ws_size,
                              hipStream_t stream) {
    const float4* p = (const float4*)d_in[0];
    const int4*   s = (const int4*)d_in[1];
    float* out = (float*)d_out;

    const int nblocks2 = COLS / 256;  // 16
    const int G = 16;
    const int NSUP = NC / G;          // 8

    float4* recs     = (float4*)d_ws;                 // NC*COLS packed 16B (8 MB)
    float4* supers   = recs + (size_t)NC * COLS;      // NSUP*COLS 32B (1 MB)
    double* partials = (double*)(supers + (size_t)NSUP * COLS * 2);

    dim3 g1(4, NC);                // 512 blocks of 256 = 2 blocks/CU
    msi_phase1<<<g1, 256, 0, stream>>>(p, s, recs);
    dim3 g2a(COLS / 256, NSUP);
    msi_phase2a<<<g2a, 256, 0, stream>>>(recs, supers, G);
    msi_phase2b<<<nblocks2, 256, 0, stream>>>(supers, partials, NSUP);
    msi_phase3<<<1, 64, 0, stream>>>(partials, nblocks2, out);
}

// Round 14
// 46.927 us; speedup vs baseline: 3.4680x; 1.0017x over previous
//
#include <hip/hip_runtime.h>

#define COLS  4096
#define C4    (COLS / 4)
#define TROWS 4096
#define PAIRS (TROWS - 1)   // 4095
#define BCOLS 1024          // cols per block
#define SR    2             // pair-rows per stage
#define NBUF  4             // ring depth
#define PCH   32            // pairs per chunk
#define NC    128           // chunks -> (4,128) = 512 blocks = 2/CU

// ---------------------------------------------------------------------------
// Mergeable run record (verified absmax=0 rounds 3-13).
// Packed 16 B: x=hs y=ts z=ms w=bits[ hc:10 | tc:10 | mc:10 | ao:2 ]
// ---------------------------------------------------------------------------
struct Rec { float hs, hc, ts, tc, ms, mc, ao; };

__device__ inline Rec rec_merge(const Rec& L, const Rec& R) {
    Rec o;
    if (L.ao != 0.f && R.ao != 0.f) {
        o.hs = L.hs + R.hs; o.hc = L.hc + R.hc;
        o.ts = o.hs;        o.tc = o.hc;
        o.ms = 0.f; o.mc = 0.f; o.ao = 1.f;
    } else if (L.ao != 0.f) {
        o.hs = L.hs + R.hs; o.hc = L.hc + R.hc;
        o.ts = R.ts; o.tc = R.tc;
        o.ms = R.ms; o.mc = R.mc; o.ao = 0.f;
    } else if (R.ao != 0.f) {
        o.hs = L.hs; o.hc = L.hc;
        o.ts = L.ts + R.hs; o.tc = L.tc + R.hc;
        o.ms = L.ms; o.mc = L.mc; o.ao = 0.f;
    } else {
        o.hs = L.hs; o.hc = L.hc;
        o.ts = R.ts; o.tc = R.tc;
        float js = L.ts + R.hs, jc = L.tc + R.hc;
        bool v = jc > 0.f;
        o.ms = L.ms + R.ms + (v ? js / jc : 0.f);
        o.mc = L.mc + R.mc + (v ? 1.f : 0.f);
        o.ao = 0.f;
    }
    return o;
}

__device__ inline Rec rec16_load(const float4* base, size_t idx) {
    float4 a = base[idx];
    unsigned u = __float_as_uint(a.w);
    Rec r;
    r.hs = a.x; r.ts = a.y; r.ms = a.z;
    r.hc = (float)(u & 1023u);
    r.tc = (float)((u >> 10) & 1023u);
    r.mc = (float)((u >> 20) & 1023u);
    r.ao = (float)(u >> 30);
    return r;
}
__device__ inline Rec rec32_load(const float4* base, size_t idx) {
    float4 a = base[idx * 2], b = base[idx * 2 + 1];
    Rec r; r.hs = a.x; r.hc = a.y; r.ts = a.z; r.tc = a.w;
    r.ms = b.x; r.mc = b.y; r.ao = b.z; return r;
}
__device__ inline void rec32_store(float4* base, size_t idx, const Rec& r) {
    base[idx * 2]     = make_float4(r.hs, r.hc, r.ts, r.tc);
    base[idx * 2 + 1] = make_float4(r.ms, r.mc, r.ao, 0.f);
}

// async 16B/lane global -> LDS with SC0|NT|SC1 cache policy (aux bit0=SC0,
// bit1=NT, bit4=SC1 on gfx950). NT alone (r13) broke the 2.8 TB/s ceiling;
// SC0+SC1 additionally makes the read system-scope = no L1/L2 allocation.
// Pure allocation/coherence hint -> semantics-neutral for read-only inputs.
__device__ __forceinline__ void async16nt(const void* g, void* l) {
    __builtin_amdgcn_global_load_lds(
        (const __attribute__((address_space(1))) void*)g,
        (__attribute__((address_space(3))) void*)l, 16, 0, 19);
}

// ---------------------------------------------------------------------------
// Phase 1: wave-private 4-deep ring (NBUF=4, SR=2) at 2 blocks/CU.
// 8 waves/CU x 12 KB/wave in flight = 96 KB/CU, zero barriers, counted vmcnt
// never drains mid-loop. Identical to r13 except aux=19 on the DMA loads.
// ---------------------------------------------------------------------------
__global__ __launch_bounds__(256)
void msi_phase1(const float4* __restrict__ p4, const int4* __restrict__ s4,
                float4* __restrict__ recs) {
    __shared__ __align__(16) float lp[NBUF][SR][BCOLS];   // 32 KB
    __shared__ __align__(16) int   lsd[NBUF][SR][BCOLS];  // 32 KB
    __shared__ __align__(16) float lpB[BCOLS];            // 4 KB
    __shared__ __align__(16) int   lsB[BCOLS];            // 4 KB

    const int tid  = threadIdx.x;
    const int wave = tid >> 6, lane = tid & 63;
    const int colq = blockIdx.x;                  // column quarter 0..3
    const int c    = blockIdx.y;                  // chunk 0..NC-1
    const int t0 = c * PCH;
    int t1 = t0 + PCH; if (t1 > PAIRS) t1 = PAIRS;
    const int nr  = t1 - t0;                      // 32 (31 last)
    const int nst = (nr + SR - 1) / SR;           // 16

    const float4* gp = p4 + colq * (BCOLS / 4) + (wave << 6) + lane;
    const int4*   gs = s4 + colq * (BCOLS / 4) + (wave << 6) + lane;
    const int woff = wave << 8;                   // wave slice: 256 floats = 1 KB

    auto issue = [&](int st) {                    // stage st: rows t0+st*SR+1 .. +SR
        int b = st & (NBUF - 1);
        #pragma unroll
        for (int j = 0; j < SR; ++j) {
            int r = t0 + st * SR + 1 + j; if (r > t1) r = t1;   // phantom, never read
            async16nt(gp + (size_t)r * C4, &lp[b][j][0] + woff);
            async16nt(gs + (size_t)r * C4, &lsd[b][j][0] + woff);
        }
    };

    float cs[4] = {0.f, 0.f, 0.f, 0.f};
    int   cc[4] = {0, 0, 0, 0};
    float hs[4] = {0.f, 0.f, 0.f, 0.f};
    int   hc[4] = {0, 0, 0, 0};
    int   hd[4] = {0, 0, 0, 0};
    float ms[4] = {0.f, 0.f, 0.f, 0.f};
    int   mc[4] = {0, 0, 0, 0};
    float pprev[4]; int sprev[4];

    // prologue: boundary row + 3 stages (14 loads outstanding)
    async16nt(gp + (size_t)t0 * C4, &lpB[0] + woff);
    async16nt(gs + (size_t)t0 * C4, &lsB[0] + woff);
    issue(0); issue(1); issue(2);                 // nst = 16 always >= 4

    for (int s = 0; s < nst; ++s) {
        // buffer being refilled = (s+3)&3; its ds_reads retired 4 iters ago.
        asm volatile("s_waitcnt lgkmcnt(0)" ::: "memory");
        if (s + 3 < nst) issue(s + 3);

        int ahead = nst - 1 - s; if (ahead > 3) ahead = 3;
        // stage s complete when outstanding <= ahead*4 (in-order vmcnt)
        if (ahead == 3)      { asm volatile("s_waitcnt vmcnt(12)" ::: "memory"); }
        else if (ahead == 2) { asm volatile("s_waitcnt vmcnt(8)"  ::: "memory"); }
        else if (ahead == 1) { asm volatile("s_waitcnt vmcnt(4)"  ::: "memory"); }
        else                 { asm volatile("s_waitcnt vmcnt(0)"  ::: "memory"); }
        __builtin_amdgcn_sched_barrier(0);

        if (s == 0) {                             // boundary row (covered by wait)
            float4 P = *(const float4*)&lpB[tid << 2];
            int4   S = *(const int4*)&lsB[tid << 2];
            pprev[0] = P.x; pprev[1] = P.y; pprev[2] = P.z; pprev[3] = P.w;
            sprev[0] = S.x; sprev[1] = S.y; sprev[2] = S.z; sprev[3] = S.w;
        }

        const int b = s & (NBUF - 1);
        int jmax = nr - s * SR; if (jmax > SR) jmax = SR;
        #pragma unroll
        for (int j = 0; j < SR; ++j) {
            if (j >= jmax) break;
            float4 PV = *(const float4*)&lp[b][j][tid << 2];
            int4   SV = *(const int4*)&lsd[b][j][tid << 2];
            float pcur[4] = {PV.x, PV.y, PV.z, PV.w};
            int   scur[4] = {SV.x, SV.y, SV.z, SV.w};
            #pragma unroll
            for (int k = 0; k < 4; ++k) {
                float d = pcur[k] - pprev[k];
                bool same = (scur[k] == sprev[k]);
                bool firstk = !same && !hd[k];
                bool interior = !same && hd[k] && (cc[k] > 0);
                hs[k] = firstk ? cs[k] : hs[k];
                hc[k] = firstk ? cc[k] : hc[k];
                float mean = cs[k] * __builtin_amdgcn_rcpf((float)cc[k]);
                ms[k] += interior ? mean : 0.f;
                mc[k] += interior ? 1 : 0;
                hd[k] = hd[k] | (same ? 0 : 1);
                cs[k] = same ? cs[k] + d * d : 0.f;
                cc[k] = same ? cc[k] + 1 : 0;
                pprev[k] = pcur[k];
                sprev[k] = scur[k];
            }
        }
    }

    // Emit 4 packed 16 B records (64 B contiguous per thread).
    #pragma unroll
    for (int k = 0; k < 4; ++k) {
        int r = colq * BCOLS + 4 * tid + k;
        float4 a;
        if (!hd[k]) {
            unsigned u = (unsigned)cc[k] | ((unsigned)cc[k] << 10) | (3u << 30);
            a = make_float4(cs[k], cs[k], 0.f, __uint_as_float(u));
        } else {
            unsigned u = (unsigned)hc[k] | ((unsigned)cc[k] << 10) |
                         ((unsigned)mc[k] << 20);
            a = make_float4(hs[k], cs[k], ms[k], __uint_as_float(u));
        }
        recs[(size_t)c * COLS + r] = a;
    }
}

// ---------------------------------------------------------------------------
// Phase 2a: merge G consecutive chunk-records per column into a 32 B super.
// ---------------------------------------------------------------------------
__global__ void msi_phase2a(const float4* __restrict__ recs, float4* __restrict__ supers,
                            int G) {
    int r = blockIdx.x * blockDim.x + threadIdx.x;
    int sup = blockIdx.y;
    size_t base = (size_t)sup * G * COLS + r;
    Rec acc = rec16_load(recs, base);
    #pragma unroll 4
    for (int j = 1; j < G; ++j) {
        Rec nxt = rec16_load(recs, base + (size_t)j * COLS);
        acc = rec_merge(acc, nxt);
    }
    rec32_store(supers, (size_t)sup * COLS + r, acc);
}

// ---------------------------------------------------------------------------
// Phase 2b: merge NSUP supers per column, finalize, block-reduce in double.
// ---------------------------------------------------------------------------
__global__ void msi_phase2b(const float4* __restrict__ supers, double* __restrict__ partials,
                            int NSUP) {
    int r = blockIdx.x * blockDim.x + threadIdx.x;
    Rec acc = rec32_load(supers, r);
    for (int j = 1; j < NSUP; ++j)
        acc = rec_merge(acc, rec32_load(supers, (size_t)j * COLS + r));

    double msum, mcnt;
    if (acc.ao != 0.f) {
        bool v = acc.hc > 0.f;
        msum = v ? (double)(acc.hs / acc.hc) : 0.0;
        mcnt = v ? 1.0 : 0.0;
    } else {
        msum = (double)acc.ms; mcnt = (double)acc.mc;
        if (acc.hc > 0.f) { msum += (double)(acc.hs / acc.hc); mcnt += 1.0; }
        if (acc.tc > 0.f) { msum += (double)(acc.ts / acc.tc); mcnt += 1.0; }
    }

    __shared__ double ls[256];
    __shared__ double lc[256];
    int tid = threadIdx.x;
    ls[tid] = msum; lc[tid] = mcnt;
    __syncthreads();
    for (int off = 128; off > 0; off >>= 1) {
        if (tid < off) { ls[tid] += ls[tid + off]; lc[tid] += lc[tid + off]; }
        __syncthreads();
    }
    if (tid == 0) {
        partials[blockIdx.x * 2 + 0] = ls[0];
        partials[blockIdx.x * 2 + 1] = lc[0];
    }
}

__global__ void msi_phase3(const double* __restrict__ partials, int nparts,
                           float* __restrict__ out) {
    int tid = threadIdx.x;
    double msum = 0.0, mcnt = 0.0;
    if (tid < nparts) {
        msum = partials[tid * 2 + 0];
        mcnt = partials[tid * 2 + 1];
    }
    for (int off = 32; off > 0; off >>= 1) {
        msum += __shfl_down(msum, off);
        mcnt += __shfl_down(mcnt, off);
    }
    if (tid == 0) out[0] = (mcnt > 0.0) ? (float)(msum / mcnt) : 0.f;
}

extern "C" void kernel_launch(void* const* d_in, const int* in_sizes, int n_in,
                              void* d_out, int out_size, void* d_ws, size_t ws_size,
                              hipStream_t stream) {
    const float4* p = (const float4*)d_in[0];
    const int4*   s = (const int4*)d_in[1];
    float* out = (float*)d_out;

    const int nblocks2 = COLS / 256;  // 16
    const int G = 16;
    const int NSUP = NC / G;          // 8

    float4* recs     = (float4*)d_ws;                 // NC*COLS packed 16B (8 MB)
    float4* supers   = recs + (size_t)NC * COLS;      // NSUP*COLS 32B (1 MB)
    double* partials = (double*)(supers + (size_t)NSUP * COLS * 2);

    dim3 g1(4, NC);                // 512 blocks of 256 = 2 blocks/CU
    msi_phase1<<<g1, 256, 0, stream>>>(p, s, recs);
    dim3 g2a(COLS / 256, NSUP);
    msi_phase2a<<<g2a, 256, 0, stream>>>(recs, supers, G);
    msi_phase2b<<<nblocks2, 256, 0, stream>>>(supers, partials, NSUP);
    msi_phase3<<<1, 64, 0, stream>>>(partials, nblocks2, out);
}